// Round 5
// baseline (499.813 us; speedup 1.0000x reference)
//
#include <hip/hip_runtime.h>
#include <hip/hip_bf16.h>
#include <cstdint>

// Problem: B*H=64, N=1024 (32x32 grid), D=256. f32 in/out; bf16 internally.
#define BH     64
#define NTOK   1024
#define DDIM   256
#define QT     128            // q rows per block (4 waves x 32 rows)
#define KTILE  32             // k tokens per iteration
#define NITER  (NTOK / KTILE) // 32

typedef __bf16 bf16x8 __attribute__((ext_vector_type(8)));
typedef float  f32x16 __attribute__((ext_vector_type(16)));

__device__ __forceinline__ unsigned short f2bf(float f) {
    __bf16 b = (__bf16)f;                       // RTNE
    return __builtin_bit_cast(unsigned short, b);
}
__device__ __forceinline__ float bf2f(unsigned short u) {
    return __builtin_bit_cast(float, ((unsigned int)u) << 16);
}
__device__ __forceinline__ unsigned int pack2(float lo, float hi) {
    return (unsigned int)f2bf(lo) | ((unsigned int)f2bf(hi) << 16);
}

// native sin/cos: v_sin/v_cos take REVOLUTIONS; reduce with fract (periodic).
__device__ __forceinline__ void sincos_rev(float rev, float* s, float* c) {
    float fr = rev - __builtin_floorf(rev);
    *s = __builtin_amdgcn_sinf(fr);
    *c = __builtin_amdgcn_cosf(fr);
}

// inv_rev[j] = 10000^(-j/64) / (2*pi) = exp2(-j*ANG_C - log2(2*pi))
#define ANG_C    (13.287712379549449f / 64.0f)
#define L2_2PI   2.6514961294723187f
// softmax: exp(s/16) = exp2(s * log2(e)/16); no max subtraction (scores bounded,
// softmax is scale-invariant; |s|/16*log2e stays within +-~25 -> f32-safe)
#define SM_SCALE (1.4426950408889634f / 16.0f)

// ---------------------------------------------------------------------------
// Kernel 1 (fused prep): blocks [0,8192): 2D RoPE on K (f32) -> KR (bf16).
//                        blocks [8192,9216): V (f32,[bh][t][d]) -> VT (bf16,[bh][d][t]).
__global__ __launch_bounds__(256) void prep(const float* __restrict__ K,
                                            const float* __restrict__ V,
                                            unsigned short* __restrict__ KR,
                                            unsigned short* __restrict__ VT) {
    __shared__ unsigned short tile[64 * 264];
    int tid = threadIdx.x;
    if (blockIdx.x < 8192) {
        // ---- RoPE on K
        int gid = blockIdx.x * 256 + tid;       // chunk id over [bh][t][32 chunks]
        int chunk = gid & 31;
        int t = (gid >> 5) & (NTOK - 1);
        float x = (float)(t & 31), y = (float)(t >> 5);
        const float4 a = *(const float4*)(K + (size_t)gid * 8);
        const float4 b = *(const float4*)(K + (size_t)gid * 8 + 4);
        float f[8] = {a.x, a.y, a.z, a.w, b.x, b.y, b.z, b.w};
        unsigned int o[4];
#pragma unroll
        for (int p = 0; p < 4; ++p) {
            int j = chunk * 4 + p;              // pair index in [0,128)
            float pos = (j < 64) ? x : y;
            float invr = __builtin_exp2f(-(float)(j & 63) * ANG_C - L2_2PI);
            float s, c;
            sincos_rev(pos * invr, &s, &c);
            float x0 = f[2 * p], x1 = f[2 * p + 1];
            o[p] = pack2(x0 * c - x1 * s, x0 * s + x1 * c);
        }
        uint4 ov; ov.x = o[0]; ov.y = o[1]; ov.z = o[2]; ov.w = o[3];
        *(uint4*)(KR + (size_t)gid * 8) = ov;
        return;
    }
    // ---- V transpose via LDS tile
    int vb = blockIdx.x - 8192;
    int bh = vb >> 4;
    int tbase = (vb & 15) * 64;
    const float* src = V + ((size_t)bh * NTOK + tbase) * DDIM;
#pragma unroll
    for (int i = 0; i < 8; ++i) {
        int flat = i * 2048 + tid * 8;
        int tl = flat >> 8, col = flat & 255;
        const float4 a = *(const float4*)(src + (size_t)tl * DDIM + col);
        const float4 b = *(const float4*)(src + (size_t)tl * DDIM + col + 4);
        uint4 ov;
        ov.x = pack2(a.x, a.y); ov.y = pack2(a.z, a.w);
        ov.z = pack2(b.x, b.y); ov.w = pack2(b.z, b.w);
        *(uint4*)(tile + tl * 264 + col) = ov;
    }
    __syncthreads();
    unsigned short* dst = VT + (size_t)bh * ((size_t)DDIM * NTOK) + tbase;
#pragma unroll
    for (int i = 0; i < 8; ++i) {
        int task = i * 256 + tid;
        int d = task >> 3, tq = task & 7;       // 8 consecutive tids -> one d row
        unsigned int o[4];
#pragma unroll
        for (int k = 0; k < 4; ++k) {
            unsigned short lo = tile[(tq * 8 + 2 * k    ) * 264 + d];
            unsigned short hi = tile[(tq * 8 + 2 * k + 1) * 264 + d];
            o[k] = (unsigned int)lo | ((unsigned int)hi << 16);
        }
        uint4 ov; ov.x = o[0]; ov.y = o[1]; ov.z = o[2]; ov.w = o[3];
        *(uint4*)(dst + (size_t)d * NTOK + tq * 8) = ov;
    }
}

// ---------------------------------------------------------------------------
// Kernel 2: flash attention, no-max softmax, 32x32x16 MFMA, SWAPPED QK^T:
//   S^T = mfma(A=K, B=Q)  -> each lane owns one q-row (col = l31) of P.
//   Softmax entirely in registers; P A-fragments built via packed shfl_xor(32).
//   O = mfma(A=P, B=V)    -> O C-layout: col = d, row = q.
// Block = 256 thr (4 waves), wave owns 32 q rows. 32 k-tiles of 32 tokens.
// REG-STAGED pipeline (T14): per iter, 8 coalesced global_load_dwordx4 ->
// regs are issued at iter start; after the compute phase, vmcnt(0) (fully
// hidden) + 8 ds_write_b128 into buf[cur^1] (swizzle on WRITE address; read
// offsets identical to the verified R4 content map); ONE s_barrier per iter
// (prev barrier already guarantees nobody still reads buf[cur^1]).
//   K buf: row r (512B), 16B-slot u stored at slot u^(r&7).
//   V buf: [256 d][32 tok]; global slot g stored at LDS slot g^((g>>3)&3).
// XCD swizzle: all 8 q-blocks of one bh land on the same XCD.
__global__ __launch_bounds__(256, 2) void flash_attn(
        const float* __restrict__ Q,
        const unsigned short* __restrict__ KR,
        const unsigned short* __restrict__ VTg,
        float* __restrict__ Out) {
    __shared__ unsigned short KT[2][KTILE * DDIM];   // 2 x 16 KiB
    __shared__ unsigned short VTl[2][DDIM * KTILE];  // 2 x 16 KiB

    const int tid = threadIdx.x;
    const int wave = tid >> 6, lane = tid & 63;
    const int l31 = lane & 31, h = lane >> 5;
    // bijective XCD-aware remap: bh = (b&7) + 8*(b>>6), q = (b>>3)&7
    const int b = blockIdx.x;
    const int bh = (b & 7) + ((b >> 6) << 3);
    const int qbase = ((b >> 3) & 7) * QT;

    const unsigned short* krB = KR + (size_t)bh * ((size_t)NTOK * DDIM);
    const unsigned short* vtB = VTg + (size_t)bh * ((size_t)DDIM * NTOK);

    // ---- staging geometry: per-wave linear slots f = wave*256 + j*64 + lane
    // global (ushort) offsets; LDS (ushort) write offsets with swizzle applied
    int kG[4], vG[4], kL[4], vL[4];
#pragma unroll
    for (int j = 0; j < 4; ++j) {
        int f = wave * 256 + j * 64 + lane;
        kG[j] = f * 8;                                  // K: linear, coalesced
        vG[j] = (f >> 2) * NTOK + (f & 3) * 8;          // V: 64B chunks, 2KB pitch
        int rf = f >> 5, sf = f & 31;
        kL[j] = rf * 256 + ((sf ^ (rf & 7)) * 8);       // K swizzled write addr
        vL[j] = (f ^ ((f >> 3) & 3)) * 8;               // V swizzled write addr
    }

    uint4 kst[4], vst[4];
    // ---- issue tile-0 loads first (hide under Q-RoPE VALU)
#pragma unroll
    for (int j = 0; j < 4; ++j) kst[j] = *(const uint4*)(krB + kG[j]);
#pragma unroll
    for (int j = 0; j < 4; ++j) vst[j] = *(const uint4*)(vtB + vG[j]);

    // ---- Q fragments (B-operand: n=l31 q-row, k-dim = d contiguous), RoPE'd
    bf16x8 qfrag[16];
    {
        const int qtok = qbase + wave * 32 + l31;
        const float x = (float)(qtok & 31), y = (float)(qtok >> 5);
        const float* qrow = Q + ((size_t)bh * NTOK + qtok) * DDIM;
#pragma unroll
        for (int cc = 0; cc < 16; ++cc) {
            const float4 a = *(const float4*)(qrow + cc * 16 + h * 8);
            const float4 b2 = *(const float4*)(qrow + cc * 16 + h * 8 + 4);
            float f[8] = {a.x, a.y, a.z, a.w, b2.x, b2.y, b2.z, b2.w};
            unsigned int po[4];
#pragma unroll
            for (int p = 0; p < 4; ++p) {
                int j = cc * 8 + h * 4 + p;     // rotary pair index in [0,128)
                float pos = (j < 64) ? x : y;
                float invr = __builtin_exp2f(-(float)(j & 63) * ANG_C - L2_2PI);
                float s, c;
                sincos_rev(pos * invr, &s, &c);
                float x0 = f[2 * p], x1 = f[2 * p + 1];
                po[p] = pack2(x0 * c - x1 * s, x0 * s + x1 * c);
            }
            uint4 pk; pk.x = po[0]; pk.y = po[1]; pk.z = po[2]; pk.w = po[3];
            qfrag[cc] = __builtin_bit_cast(bf16x8, pk);
        }
    }

    f32x16 o[8] = {};                           // O accum: col=d (l31), row=q
    float lsum[4] = {};                         // per-lane (q=l31) denom partials

    // ---- per-lane read offsets (identical content map to R4, verified)
    const int kx = l31 & 7;                     // K read XOR key
    const int vx = (l31 >> 1) & 3;              // V read XOR key
    const int vbase = l31 * 32;                 // d-row base within nt-chunk
    const int vh0 = (h ^ vx) * 8;               // tok-chunk 0 slot
    const int vh1 = ((2 + h) ^ vx) * 8;         // tok-chunk 1 slot

    // ---- prologue: land tile 0 into buf0, issue tile-1 loads, barrier
    asm volatile("s_waitcnt vmcnt(0)" ::: "memory");
#pragma unroll
    for (int j = 0; j < 4; ++j) *(uint4*)(&KT[0][kL[j]]) = kst[j];
#pragma unroll
    for (int j = 0; j < 4; ++j) *(uint4*)(&VTl[0][vL[j]]) = vst[j];
#pragma unroll
    for (int j = 0; j < 4; ++j) kst[j] = *(const uint4*)(krB + KTILE * DDIM + kG[j]);
#pragma unroll
    for (int j = 0; j < 4; ++j) vst[j] = *(const uint4*)(vtB + KTILE + vG[j]);
    asm volatile("s_waitcnt lgkmcnt(0)" ::: "memory");
    __builtin_amdgcn_s_barrier();

    for (int it = 0; it < NITER; ++it) {
        const int cur = it & 1;

        // ---- S^T = K_rope . Q_rope^T  (A=K: m=tok, B=Q: n=q-row)
        //      two independent MFMA chains to halve dependent latency
        f32x16 sca = {}, scb = {};
        const unsigned short* ktb = KT[cur];
#pragma unroll
        for (int cc = 0; cc < 8; ++cc) {
            const int sla = ((2 * cc + h) ^ kx) * 8;
            const int slb = ((2 * (cc + 8) + h) ^ kx) * 8;
            bf16x8 ka = *(const bf16x8*)(ktb + l31 * 256 + sla);
            bf16x8 kb_ = *(const bf16x8*)(ktb + l31 * 256 + slb);
            sca = __builtin_amdgcn_mfma_f32_32x32x16_bf16(ka, qfrag[cc], sca, 0, 0, 0);
            scb = __builtin_amdgcn_mfma_f32_32x32x16_bf16(kb_, qfrag[cc + 8], scb, 0, 0, 0);
        }
        f32x16 sc = sca + scb;

        // ---- P = exp2(S * SM_SCALE), all in registers; lane owns q=l31,
        //      holds k = (r&3)+8*(r>>2)+4h. Accumulate rounded-P denominator.
        unsigned short bs[16];
#pragma unroll
        for (int r = 0; r < 16; ++r) {
            float p = __builtin_exp2f(sc[r] * SM_SCALE);
            bs[r] = f2bf(p);
            lsum[r & 3] += bf2f(bs[r]);
        }
        // ---- build P A-fragments (m=q=l31, k = h*8+0..7 per 16-chunk) via
        //      packed half-swap: partner (lane^32) holds the other 4-aligned ks.
        bf16x8 pa[2];
#pragma unroll
        for (int c = 0; c < 2; ++c) {
            unsigned int P1 = (unsigned)bs[c*8+0] | ((unsigned)bs[c*8+1] << 16);
            unsigned int P2 = (unsigned)bs[c*8+2] | ((unsigned)bs[c*8+3] << 16);
            unsigned int P3 = (unsigned)bs[c*8+4] | ((unsigned)bs[c*8+5] << 16);
            unsigned int P4 = (unsigned)bs[c*8+6] | ((unsigned)bs[c*8+7] << 16);
            unsigned int P1x = __shfl_xor((int)P1, 32);
            unsigned int P2x = __shfl_xor((int)P2, 32);
            unsigned int P3x = __shfl_xor((int)P3, 32);
            unsigned int P4x = __shfl_xor((int)P4, 32);
            uint4 w;
            w.x = h ? P3x : P1;
            w.y = h ? P4x : P2;
            w.z = h ? P3  : P1x;
            w.w = h ? P4  : P2x;
            pa[c] = __builtin_bit_cast(bf16x8, w);
        }

        // ---- O += P . V   (B = V[k=tok][n=d]: lane = d-row nt*32+l31)
        const unsigned short* vtb = VTl[cur];
#pragma unroll
        for (int nt = 0; nt < 8; ++nt) {
            const unsigned short* vp = vtb + nt * 1024 + vbase;
            bf16x8 v0 = *(const bf16x8*)(vp + vh0);
            bf16x8 v1 = *(const bf16x8*)(vp + vh1);
            o[nt] = __builtin_amdgcn_mfma_f32_32x32x16_bf16(pa[0], v0, o[nt], 0, 0, 0);
            o[nt] = __builtin_amdgcn_mfma_f32_32x32x16_bf16(pa[1], v1, o[nt], 0, 0, 0);
        }

        // ---- stage tile it+1 into buf[cur^1]; issue loads for tile it+2
        if (it + 1 < NITER) {
            const int nxt = cur ^ 1;
            asm volatile("s_waitcnt vmcnt(0)" ::: "memory");  // regs landed (hidden)
#pragma unroll
            for (int j = 0; j < 4; ++j) *(uint4*)(&KT[nxt][kL[j]]) = kst[j];
#pragma unroll
            for (int j = 0; j < 4; ++j) *(uint4*)(&VTl[nxt][vL[j]]) = vst[j];
            if (it + 2 < NITER) {
                const int kb2 = (it + 2) * KTILE;
#pragma unroll
                for (int j = 0; j < 4; ++j)
                    kst[j] = *(const uint4*)(krB + kb2 * DDIM + kG[j]);
#pragma unroll
                for (int j = 0; j < 4; ++j)
                    vst[j] = *(const uint4*)(vtB + kb2 + vG[j]);
            }
            asm volatile("s_waitcnt lgkmcnt(0)" ::: "memory");
            __builtin_amdgcn_s_barrier();       // buf[nxt] visible to all waves
        }
    }

    // ---- epilogue: lane's denom = own half + partner half (same q = l31)
    float tot = (lsum[0] + lsum[1]) + (lsum[2] + lsum[3]);
    tot += __shfl_xor(tot, 32);
    // O rows are q = (r&3)+8*(r>>2)+4h; fetch that q's denom from lane q.
#pragma unroll
    for (int r = 0; r < 16; ++r) {
        const int q = (r & 3) + 8 * (r >> 2) + 4 * h;
        float rl = 1.0f / __shfl(tot, q);
        float* orow =
            Out + ((size_t)bh * NTOK + qbase + wave * 32 + q) * DDIM;
#pragma unroll
        for (int nt = 0; nt < 8; ++nt)
            orow[nt * 32 + l31] = o[nt][r] * rl;
    }
}

// ---------------------------------------------------------------------------
extern "C" void kernel_launch(void* const* d_in, const int* in_sizes, int n_in,
                              void* d_out, int out_size, void* d_ws, size_t ws_size,
                              hipStream_t stream) {
    const float* Q = (const float*)d_in[0];
    const float* K = (const float*)d_in[1];
    const float* V = (const float*)d_in[2];
    unsigned short* KR = (unsigned short*)d_ws;                       // 33.5 MB bf16
    unsigned short* VT = KR + (size_t)BH * NTOK * DDIM;               // 33.5 MB bf16
    float* O = (float*)d_out;

    prep<<<8192 + BH * (NTOK / 64), 256, 0, stream>>>(K, V, KR, VT);
    flash_attn<<<BH * (NTOK / QT), 256, 0, stream>>>(Q, KR, VT, O);
}

// Round 6
// 304.000 us; speedup vs baseline: 1.6441x; 1.6441x over previous
//
#include <hip/hip_runtime.h>
#include <hip/hip_bf16.h>
#include <cstdint>

// Problem: B*H=64, N=1024 (32x32 grid), D=256. f32 in/out; bf16 internally.
#define BH     64
#define NTOK   1024
#define DDIM   256
#define QT     128            // q rows per block (4 waves x 32 rows)
#define KTILE  32             // k tokens per iteration
#define NITER  (NTOK / KTILE) // 32

typedef __bf16 bf16x8 __attribute__((ext_vector_type(8)));
typedef float  f32x16 __attribute__((ext_vector_type(16)));

__device__ __forceinline__ unsigned short f2bf(float f) {
    __bf16 b = (__bf16)f;                       // RTNE
    return __builtin_bit_cast(unsigned short, b);
}
__device__ __forceinline__ float bf2f(unsigned short u) {
    return __builtin_bit_cast(float, ((unsigned int)u) << 16);
}
__device__ __forceinline__ unsigned int pack2(float lo, float hi) {
    return (unsigned int)f2bf(lo) | ((unsigned int)f2bf(hi) << 16);
}

// native sin/cos: v_sin/v_cos take REVOLUTIONS; reduce with fract (periodic).
__device__ __forceinline__ void sincos_rev(float rev, float* s, float* c) {
    float fr = rev - __builtin_floorf(rev);
    *s = __builtin_amdgcn_sinf(fr);
    *c = __builtin_amdgcn_cosf(fr);
}

// async global->LDS, 16B per lane; LDS dest must be wave-uniform base (+lane*16)
typedef const __attribute__((address_space(1))) unsigned int* gas_t;
typedef __attribute__((address_space(3))) unsigned int* las_t;
__device__ __forceinline__ void gload16(const void* g, void* l) {
    __builtin_amdgcn_global_load_lds((gas_t)g, (las_t)l, 16, 0, 0);
}

// inv_rev[j] = 10000^(-j/64) / (2*pi) = exp2(-j*ANG_C - log2(2*pi))
#define ANG_C    (13.287712379549449f / 64.0f)
#define L2_2PI   2.6514961294723187f
// softmax: exp(s/16) = exp2(s * log2(e)/16); no max subtraction (scores bounded,
// softmax is scale-invariant; |s|/16*log2e stays within +-~25 -> f32-safe)
#define SM_SCALE (1.4426950408889634f / 16.0f)

// ---------------------------------------------------------------------------
// Kernel 1: 2D RoPE on K (f32) -> KR (bf16, same [bh][t][d] layout). No LDS.
__global__ __launch_bounds__(256) void rope_k(const float* __restrict__ K,
                                              unsigned short* __restrict__ KR) {
    int gid = blockIdx.x * 256 + threadIdx.x;   // chunk id over [bh][t][32 chunks]
    int chunk = gid & 31;
    int t = (gid >> 5) & (NTOK - 1);
    float x = (float)(t & 31), y = (float)(t >> 5);
    const float4 a = *(const float4*)(K + (size_t)gid * 8);
    const float4 b = *(const float4*)(K + (size_t)gid * 8 + 4);
    float f[8] = {a.x, a.y, a.z, a.w, b.x, b.y, b.z, b.w};
    unsigned int o[4];
#pragma unroll
    for (int p = 0; p < 4; ++p) {
        int j = chunk * 4 + p;                  // pair index in [0,128)
        float pos = (j < 64) ? x : y;
        float invr = __builtin_exp2f(-(float)(j & 63) * ANG_C - L2_2PI);
        float s, c;
        sincos_rev(pos * invr, &s, &c);
        float x0 = f[2 * p], x1 = f[2 * p + 1];
        o[p] = pack2(x0 * c - x1 * s, x0 * s + x1 * c);
    }
    uint4 ov; ov.x = o[0]; ov.y = o[1]; ov.z = o[2]; ov.w = o[3];
    *(uint4*)(KR + (size_t)gid * 8) = ov;
}

// ---------------------------------------------------------------------------
// Kernel 2: V (f32, [bh][t][d]) -> VT (bf16, [bh][d][t]) via LDS tile.
__global__ __launch_bounds__(256) void transpose_v(const float* __restrict__ V,
                                                   unsigned short* __restrict__ VT) {
    __shared__ unsigned short tile[64 * 264];
    int tid = threadIdx.x;
    int bh = blockIdx.x >> 4;
    int tbase = (blockIdx.x & 15) * 64;
    const float* src = V + ((size_t)bh * NTOK + tbase) * DDIM;
#pragma unroll
    for (int i = 0; i < 8; ++i) {
        int flat = i * 2048 + tid * 8;
        int tl = flat >> 8, col = flat & 255;
        const float4 a = *(const float4*)(src + (size_t)tl * DDIM + col);
        const float4 b = *(const float4*)(src + (size_t)tl * DDIM + col + 4);
        uint4 ov;
        ov.x = pack2(a.x, a.y); ov.y = pack2(a.z, a.w);
        ov.z = pack2(b.x, b.y); ov.w = pack2(b.z, b.w);
        *(uint4*)(tile + tl * 264 + col) = ov;
    }
    __syncthreads();
    unsigned short* dst = VT + (size_t)bh * ((size_t)DDIM * NTOK) + tbase;
#pragma unroll
    for (int i = 0; i < 8; ++i) {
        int task = i * 256 + tid;
        int d = task >> 3, tq = task & 7;       // 8 consecutive tids -> one d row
        unsigned int o[4];
#pragma unroll
        for (int k = 0; k < 4; ++k) {
            unsigned short lo = tile[(tq * 8 + 2 * k    ) * 264 + d];
            unsigned short hi = tile[(tq * 8 + 2 * k + 1) * 264 + d];
            o[k] = (unsigned int)lo | ((unsigned int)hi << 16);
        }
        uint4 ov; ov.x = o[0]; ov.y = o[1]; ov.z = o[2]; ov.w = o[3];
        *(uint4*)(dst + (size_t)d * NTOK + tq * 8) = ov;
    }
}

// ---------------------------------------------------------------------------
// Kernel 3: flash attention, no-max softmax, 32x32x16 MFMA, SWAPPED QK^T
// (verified R4 structure, register-neutral: arch 128 + acc ~144 stays under
// the 2-waves/SIMD cap; any addition spills — measured R5 regression).
//   S^T = mfma(A=K, B=Q)  -> each lane owns one q-row (col = l31) of P.
//   Softmax entirely in registers; P A-fragments built via packed shfl_xor(32).
//   O = mfma(A=P, B=V)    -> O C-layout: col = d, row = q.
// Block = 256 thr (4 waves), wave owns 32 q rows. 32 k-tiles of 32 tokens.
// Double-buffered global_load_lds staging, counted vmcnt(8), raw s_barriers.
//   K buf: row r (512B), 16B-slot u stored at u^(r&7).
//   V buf: [256 d][32 tok]; global slot g stored at g^((g>>3)&3).
// XCD swizzle: all 8 q-blocks of one bh land on the same XCD.
__global__ __launch_bounds__(256, 2) void flash_attn(
        const float* __restrict__ Q,
        const unsigned short* __restrict__ KR,
        const unsigned short* __restrict__ VTg,
        float* __restrict__ Out) {
    __shared__ unsigned short KT[2][KTILE * DDIM];   // 2 x 16 KiB
    __shared__ unsigned short VTl[2][DDIM * KTILE];  // 2 x 16 KiB

    const int tid = threadIdx.x;
    const int wave = tid >> 6, lane = tid & 63;
    const int l31 = lane & 31, h = lane >> 5;
    // bijective XCD-aware remap: bh = (b&7) + 8*(b>>6), q = (b>>3)&7
    const int b = blockIdx.x;
    const int bh = (b & 7) + ((b >> 6) << 3);
    const int qbase = ((b >> 3) & 7) * QT;

    const unsigned short* krB = KR + (size_t)bh * ((size_t)NTOK * DDIM);
    const unsigned short* vtB = VTg + (size_t)bh * ((size_t)DDIM * NTOK);

    // ---- Q fragments (B-operand: n=l31 q-row, k-dim = d contiguous), RoPE'd
    bf16x8 qfrag[16];
    {
        const int qtok = qbase + wave * 32 + l31;
        const float x = (float)(qtok & 31), y = (float)(qtok >> 5);
        const float* qrow = Q + ((size_t)bh * NTOK + qtok) * DDIM;
#pragma unroll
        for (int cc = 0; cc < 16; ++cc) {
            const float4 a = *(const float4*)(qrow + cc * 16 + h * 8);
            const float4 b2 = *(const float4*)(qrow + cc * 16 + h * 8 + 4);
            float f[8] = {a.x, a.y, a.z, a.w, b2.x, b2.y, b2.z, b2.w};
            unsigned int po[4];
#pragma unroll
            for (int p = 0; p < 4; ++p) {
                int j = cc * 8 + h * 4 + p;     // rotary pair index in [0,128)
                float pos = (j < 64) ? x : y;
                float invr = __builtin_exp2f(-(float)(j & 63) * ANG_C - L2_2PI);
                float s, c;
                sincos_rev(pos * invr, &s, &c);
                float x0 = f[2 * p], x1 = f[2 * p + 1];
                po[p] = pack2(x0 * c - x1 * s, x0 * s + x1 * c);
            }
            uint4 pk; pk.x = po[0]; pk.y = po[1]; pk.z = po[2]; pk.w = po[3];
            qfrag[cc] = __builtin_bit_cast(bf16x8, pk);
        }
    }
    // drain Q loads so the counted-vmcnt staging accounting below is exact
    asm volatile("s_waitcnt vmcnt(0)" ::: "memory");

    f32x16 o[8] = {};                           // O accum: col=d (l31), row=q
    float lsum[4] = {};                         // per-lane (q=l31) denom partials

    // ---- per-lane staging source offsets (ushort units; add kb term per iter)
    // Linear dest slot f = wave*256 + j*64 + lane over the 1024 16B-slots.
    int kOff[4], vOff[4];
#pragma unroll
    for (int j = 0; j < 4; ++j) {
        int f = wave * 256 + j * 64 + lane;
        int rf = f >> 5, sf = f & 31;           // K: row, 16B slot (involution)
        kOff[j] = rf * 256 + ((sf ^ (rf & 7)) * 8);
        int gI = f ^ ((f >> 3) & 3);            // V: involution on slot bits 0-1
        vOff[j] = (gI >> 2) * NTOK + (gI & 3) * 8;
    }
    // ---- per-lane read offsets
    const int kx = l31 & 7;                     // K read XOR key
    const int vx = (l31 >> 1) & 3;              // V read XOR key
    const int vbase = l31 * 32;                 // d-row base within nt-chunk
    const int vh0 = (h ^ vx) * 8;               // tok-chunk 0 slot
    const int vh1 = ((2 + h) ^ vx) * 8;         // tok-chunk 1 slot

    // ---- prologue: stage tile 0 into buffer 0 (8 loads in flight)
#pragma unroll
    for (int j = 0; j < 4; ++j)
        gload16(krB + kOff[j], &KT[0][wave * 2048 + j * 512]);
#pragma unroll
    for (int j = 0; j < 4; ++j)
        gload16(vtB + vOff[j], &VTl[0][wave * 2048 + j * 512]);

    for (int it = 0; it < NITER; ++it) {
        const int cur = it & 1;
        if (it + 1 < NITER) {                   // issue next tile's 8 loads
            const int kb = (it + 1) * KTILE;
            const unsigned short* krT = krB + (size_t)kb * DDIM;
            const unsigned short* vtT = vtB + kb;
            const int nxt = cur ^ 1;
#pragma unroll
            for (int j = 0; j < 4; ++j)
                gload16(krT + kOff[j], &KT[nxt][wave * 2048 + j * 512]);
#pragma unroll
            for (int j = 0; j < 4; ++j)
                gload16(vtT + vOff[j], &VTl[nxt][wave * 2048 + j * 512]);
            asm volatile("s_waitcnt vmcnt(8)" ::: "memory");  // cur tile landed
        } else {
            asm volatile("s_waitcnt vmcnt(0)" ::: "memory");
        }
        __builtin_amdgcn_s_barrier();           // cur buffers full for all waves

        // ---- S^T = K_rope . Q_rope^T  (A=K: m=tok, B=Q: n=q-row)
        f32x16 sc = {};
        const unsigned short* ktb = KT[cur];
        __builtin_amdgcn_s_setprio(1);
#pragma unroll
        for (int cc = 0; cc < 16; ++cc) {
            const int sl = ((2 * cc + h) ^ kx) * 8;
            bf16x8 kb_ = *(const bf16x8*)(ktb + l31 * 256 + sl);
            sc = __builtin_amdgcn_mfma_f32_32x32x16_bf16(kb_, qfrag[cc], sc, 0, 0, 0);
        }
        __builtin_amdgcn_s_setprio(0);

        // ---- P = exp2(S * SM_SCALE), all in registers; lane owns q=l31,
        //      holds k = (r&3)+8*(r>>2)+4h. Accumulate rounded-P denominator.
        unsigned short bs[16];
#pragma unroll
        for (int r = 0; r < 16; ++r) {
            float p = __builtin_exp2f(sc[r] * SM_SCALE);
            bs[r] = f2bf(p);
            lsum[r & 3] += bf2f(bs[r]);
        }
        // ---- build P A-fragments (m=q=l31, k = h*8+0..7 per 16-chunk) via
        //      packed half-swap: partner (lane^32) holds the other 4-aligned ks.
        bf16x8 pa[2];
#pragma unroll
        for (int c = 0; c < 2; ++c) {
            unsigned int P1 = (unsigned)bs[c*8+0] | ((unsigned)bs[c*8+1] << 16);
            unsigned int P2 = (unsigned)bs[c*8+2] | ((unsigned)bs[c*8+3] << 16);
            unsigned int P3 = (unsigned)bs[c*8+4] | ((unsigned)bs[c*8+5] << 16);
            unsigned int P4 = (unsigned)bs[c*8+6] | ((unsigned)bs[c*8+7] << 16);
            unsigned int P1x = __shfl_xor((int)P1, 32);
            unsigned int P2x = __shfl_xor((int)P2, 32);
            unsigned int P3x = __shfl_xor((int)P3, 32);
            unsigned int P4x = __shfl_xor((int)P4, 32);
            uint4 w;
            w.x = h ? P3x : P1;
            w.y = h ? P4x : P2;
            w.z = h ? P3  : P1x;
            w.w = h ? P4  : P2x;
            pa[c] = __builtin_bit_cast(bf16x8, w);
        }

        // ---- O += P . V   (B = V[k=tok][n=d]: lane = d-row nt*32+l31)
        const unsigned short* vtb = VTl[cur];
        __builtin_amdgcn_s_setprio(1);
#pragma unroll
        for (int nt = 0; nt < 8; ++nt) {
            const unsigned short* vp = vtb + nt * 1024 + vbase;
            bf16x8 v0 = *(const bf16x8*)(vp + vh0);
            bf16x8 v1 = *(const bf16x8*)(vp + vh1);
            o[nt] = __builtin_amdgcn_mfma_f32_32x32x16_bf16(pa[0], v0, o[nt], 0, 0, 0);
            o[nt] = __builtin_amdgcn_mfma_f32_32x32x16_bf16(pa[1], v1, o[nt], 0, 0, 0);
        }
        __builtin_amdgcn_s_setprio(0);

        asm volatile("s_waitcnt lgkmcnt(0)" ::: "memory");  // LDS reads done
        __builtin_amdgcn_s_barrier();           // safe to overwrite cur^1 next
    }

    // ---- epilogue: lane's denom = own half + partner half (same q = l31)
    float tot = (lsum[0] + lsum[1]) + (lsum[2] + lsum[3]);
    tot += __shfl_xor(tot, 32);
    // O rows are q = (r&3)+8*(r>>2)+4h; fetch that q's denom from lane q.
#pragma unroll
    for (int r = 0; r < 16; ++r) {
        const int q = (r & 3) + 8 * (r >> 2) + 4 * h;
        float rl = 1.0f / __shfl(tot, q);
        float* orow =
            Out + ((size_t)bh * NTOK + qbase + wave * 32 + q) * DDIM;
#pragma unroll
        for (int nt = 0; nt < 8; ++nt)
            orow[nt * 32 + l31] = o[nt][r] * rl;
    }
}

// ---------------------------------------------------------------------------
extern "C" void kernel_launch(void* const* d_in, const int* in_sizes, int n_in,
                              void* d_out, int out_size, void* d_ws, size_t ws_size,
                              hipStream_t stream) {
    const float* Q = (const float*)d_in[0];
    const float* K = (const float*)d_in[1];
    const float* V = (const float*)d_in[2];
    unsigned short* KR = (unsigned short*)d_ws;                       // 33.5 MB bf16
    unsigned short* VT = KR + (size_t)BH * NTOK * DDIM;               // 33.5 MB bf16
    float* O = (float*)d_out;

    rope_k<<<(BH * NTOK * DDIM / 8) / 256, 256, 0, stream>>>(K, KR);
    transpose_v<<<BH * (NTOK / 64), 256, 0, stream>>>(V, VT);
    flash_attn<<<BH * (NTOK / QT), 256, 0, stream>>>(Q, KR, VT, O);
}